// Round 3
// baseline (790.651 us; speedup 1.0000x reference)
//
#include <hip/hip_runtime.h>
#include <float.h>
#include <math.h>

#define NB 8
#define P1 4097
#define NP 4096
#define NC 1024
#define NT 256
#define NNON 3840
#define NKP 32

// ---------------- Stage 1: attn = q[:,0]·k / 32  and  invnorm of k rows ----------------
__global__ __launch_bounds__(256) void attn_norm_kernel(const float* __restrict__ q,
                                                        const float* __restrict__ kk,
                                                        float* __restrict__ attn,
                                                        float* __restrict__ invn) {
  int gid = blockIdx.x * blockDim.x + threadIdx.x;
  int gw = gid >> 6;
  int lane = gid & 63;
  if (gw >= NB * P1) return;
  int b = gw / P1;
  int p = gw - b * P1;
  const float4* kr = (const float4*)(kk + ((size_t)b * P1 + p) * NC);
  const float4* qr = (const float4*)(q + (size_t)b * P1 * NC);  // row 0 of q
  float dot = 0.f, nrm = 0.f;
#pragma unroll
  for (int i = 0; i < 4; i++) {
    int idx = lane + i * 64;
    float4 kv = kr[idx];
    float4 qv = qr[idx];
    dot += kv.x * qv.x + kv.y * qv.y + kv.z * qv.z + kv.w * qv.w;
    nrm += kv.x * kv.x + kv.y * kv.y + kv.z * kv.z + kv.w * kv.w;
  }
#pragma unroll
  for (int off = 32; off >= 1; off >>= 1) {
    dot += __shfl_down(dot, off);
    nrm += __shfl_down(nrm, off);
  }
  if (lane == 0) {
    attn[gw] = dot * 0.03125f;                       // * C^-0.5 = 1/32
    invn[gw] = 1.0f / fmaxf(sqrtf(nrm), 1e-12f);     // l2norm denom w/ EPS_NORM
  }
}

// ---------------- Stage 2: softmax over P1 per batch ----------------
__global__ __launch_bounds__(256) void softmax_kernel(const float* __restrict__ attn,
                                                      float* __restrict__ cls) {
  __shared__ float red[256];
  int b = blockIdx.x, t = threadIdx.x;
  const float* a = attn + (size_t)b * P1;
  float mx = -FLT_MAX;
  for (int i = t; i < P1; i += 256) mx = fmaxf(mx, a[i]);
  red[t] = mx;
  __syncthreads();
  for (int s = 128; s >= 1; s >>= 1) {
    if (t < s) red[t] = fmaxf(red[t], red[t + s]);
    __syncthreads();
  }
  mx = red[0];
  __syncthreads();
  float sm = 0.f;
  for (int i = t; i < P1; i += 256) sm += expf(a[i] - mx);
  red[t] = sm;
  __syncthreads();
  for (int s = 128; s >= 1; s >>= 1) {
    if (t < s) red[t] += red[t + s];
    __syncthreads();
  }
  float inv = 1.0f / red[0];
  for (int i = t; i < P1; i += 256) cls[(size_t)b * P1 + i] = expf(a[i] - mx) * inv;
}

// ---------------- Stage 3: top-256 (desc, stable) + sorted complement ----------------
__global__ __launch_bounds__(256) void topk_kernel(const float* __restrict__ cls,
                                                   int* __restrict__ tki,
                                                   int* __restrict__ nni) {
  __shared__ float sval[NP];
  __shared__ int sidx[NP];
  __shared__ unsigned char mark[NP];
  __shared__ int cnt[256];
  int b = blockIdx.x, t = threadIdx.x;
  for (int i = t; i < NP; i += 256) {
    sval[i] = cls[(size_t)b * P1 + 1 + i];
    sidx[i] = i;
  }
  __syncthreads();
  // bitonic sort, order: value desc, index asc (matches jax.lax.top_k)
  for (int size = 2; size <= NP; size <<= 1) {
    for (int stride = size >> 1; stride >= 1; stride >>= 1) {
      for (int vt = t; vt < NP; vt += 256) {
        int l = vt ^ stride;
        if (l > vt) {
          float v1 = sval[vt], v2 = sval[l];
          int i1 = sidx[vt], i2 = sidx[l];
          bool l_before = (v2 > v1) || (v2 == v1 && i2 < i1);
          bool asc = ((vt & size) == 0);
          if (asc == l_before) {
            sval[vt] = v2; sval[l] = v1;
            sidx[vt] = i2; sidx[l] = i1;
          }
        }
      }
      __syncthreads();
    }
  }
  for (int i = t; i < NP; i += 256) mark[i] = 0;
  __syncthreads();
  if (t < NT) {
    int id = sidx[t];
    tki[b * NT + t] = id;
    mark[id] = 1;
  }
  __syncthreads();
  int base = t * 16, c = 0;
#pragma unroll
  for (int i = 0; i < 16; i++) c += (mark[base + i] ? 0 : 1);
  cnt[t] = c;
  __syncthreads();
  for (int s = 1; s < 256; s <<= 1) {
    int v = (t >= s) ? cnt[t - s] : 0;
    __syncthreads();
    cnt[t] += v;
    __syncthreads();
  }
  int pos = cnt[t] - c;
  for (int i = 0; i < 16; i++) {
    int idx = base + i;
    if (!mark[idx]) nni[b * NNON + pos++] = idx;
  }
}

// ---------------- Stage 4: sim = (topk_keys · non_keysᵀ) scaled by inv norms ----------------
// fp32 vector GEMM, M=256 N=3840 K=1024, tile 128x128, micro 8x8, K-chunk 8
__global__ __launch_bounds__(256) void sim_gemm_kernel(const float* __restrict__ kk,
                                                       const int* __restrict__ tki,
                                                       const int* __restrict__ nni,
                                                       const float* __restrict__ invn,
                                                       float* __restrict__ sim) {
  __shared__ float As[8][128];
  __shared__ float Bs[8][128];
  __shared__ size_t arow[128];
  __shared__ size_t brow[128];
  int b = blockIdx.z;
  int m0 = blockIdx.y * 128;
  int n0 = blockIdx.x * 128;
  int t = threadIdx.x;
  if (t < 128)
    arow[t] = ((size_t)b * P1 + 1 + tki[b * NT + m0 + t]) * NC;
  else
    brow[t - 128] = ((size_t)b * P1 + 1 + nni[b * NNON + n0 + (t - 128)]) * NC;
  __syncthreads();
  float acc[8][8];
#pragma unroll
  for (int i = 0; i < 8; i++)
#pragma unroll
    for (int j = 0; j < 8; j++) acc[i][j] = 0.f;
  int tx = t & 15, ty = t >> 4;
  int r = t & 127;
  for (int k0 = 0; k0 < NC; k0 += 8) {
    const float* src = kk + (t < 128 ? arow[r] : brow[r]) + k0;
    float4 v0 = ((const float4*)src)[0];
    float4 v1 = ((const float4*)src)[1];
    float(*dst)[128] = (t < 128) ? As : Bs;
    dst[0][r] = v0.x; dst[1][r] = v0.y; dst[2][r] = v0.z; dst[3][r] = v0.w;
    dst[4][r] = v1.x; dst[5][r] = v1.y; dst[6][r] = v1.z; dst[7][r] = v1.w;
    __syncthreads();
#pragma unroll
    for (int kq = 0; kq < 8; kq++) {
      float4 a0 = *(const float4*)&As[kq][ty * 8];
      float4 a1 = *(const float4*)&As[kq][ty * 8 + 4];
      float4 b0 = *(const float4*)&Bs[kq][tx * 8];
      float4 b1 = *(const float4*)&Bs[kq][tx * 8 + 4];
      float av[8] = {a0.x, a0.y, a0.z, a0.w, a1.x, a1.y, a1.z, a1.w};
      float bv[8] = {b0.x, b0.y, b0.z, b0.w, b1.x, b1.y, b1.z, b1.w};
#pragma unroll
      for (int i = 0; i < 8; i++)
#pragma unroll
        for (int j = 0; j < 8; j++) acc[i][j] = fmaf(av[i], bv[j], acc[i][j]);
    }
    __syncthreads();
  }
  float rinv[8], cinv[8];
#pragma unroll
  for (int i = 0; i < 8; i++) rinv[i] = invn[arow[ty * 8 + i] / NC];
#pragma unroll
  for (int j = 0; j < 8; j++) cinv[j] = invn[brow[tx * 8 + j] / NC];
#pragma unroll
  for (int i = 0; i < 8; i++) {
    size_t o = ((size_t)b * NT + m0 + ty * 8 + i) * (size_t)NNON + n0 + tx * 8;
    float4 r0, r1;
    r0.x = acc[i][0] * rinv[i] * cinv[0];
    r0.y = acc[i][1] * rinv[i] * cinv[1];
    r0.z = acc[i][2] * rinv[i] * cinv[2];
    r0.w = acc[i][3] * rinv[i] * cinv[3];
    r1.x = acc[i][4] * rinv[i] * cinv[4];
    r1.y = acc[i][5] * rinv[i] * cinv[5];
    r1.z = acc[i][6] * rinv[i] * cinv[6];
    r1.w = acc[i][7] * rinv[i] * cinv[7];
    *(float4*)(sim + o) = r0;
    *(float4*)(sim + o + 4) = r1;
  }
}

// ---------------- Stage 5: per (b,t) top-32 of sim row + weighted merge ----------------
__global__ __launch_bounds__(256) void merge_kernel(const float* __restrict__ ff,
                                                    const float* __restrict__ sim,
                                                    const float* __restrict__ cls,
                                                    const int* __restrict__ tki,
                                                    const int* __restrict__ nni,
                                                    float* __restrict__ out) {
  __shared__ float rv[256];
  __shared__ int rn[256];
  __shared__ int sel[NKP];
  __shared__ int sp[NKP];
  __shared__ float saw[NKP + 1];
  int b = blockIdx.x >> 8;
  int tt = blockIdx.x & 255;
  int t = threadIdx.x;
  const float* simrow = sim + ((size_t)b * NT + tt) * (size_t)NNON;
  const int* nidx = nni + b * NNON;
  float v[15];
#pragma unroll
  for (int i = 0; i < 15; i++) v[i] = simrow[t + i * 256];
  for (int it = 0; it < NKP; it++) {
    float bv = -FLT_MAX;
    int bn = 1 << 30;
#pragma unroll
    for (int i = 0; i < 15; i++) {
      if (v[i] > bv) { bv = v[i]; bn = t + i * 256; }
    }
    rv[t] = bv; rn[t] = bn;
    __syncthreads();
    for (int s = 128; s >= 1; s >>= 1) {
      if (t < s) {
        if (rv[t + s] > rv[t] || (rv[t + s] == rv[t] && rn[t + s] < rn[t])) {
          rv[t] = rv[t + s];
          rn[t] = rn[t + s];
        }
      }
      __syncthreads();
    }
    int win = rn[0];
    __syncthreads();
    if (t == (win & 255)) v[win >> 8] = -FLT_MAX;
    if (t == 0) sel[it] = win;
  }
  __syncthreads();
  if (t < NKP) {
    int n = sel[t];
    int p = nidx[n];
    sp[t] = p;
    saw[t] = cls[(size_t)b * P1 + 1 + p];
  }
  __syncthreads();
  if (t == 0) {
    float s = 0.f;
    for (int j = 0; j < NKP; j++) s += saw[j];
    saw[NKP] = s;
  }
  __syncthreads();
  float wden = saw[NKP] + 1e-6f;
  int tfrow = tki[b * NT + tt];
  for (int c = t; c < NC; c += 256) {
    float acc = 0.f;
#pragma unroll 4
    for (int j = 0; j < NKP; j++)
      acc += saw[j] * ff[((size_t)b * P1 + 1 + sp[j]) * NC + c];
    float wavg = acc / wden;
    float tf = ff[((size_t)b * P1 + 1 + tfrow) * NC + c];
    out[((size_t)b * 257 + 1 + tt) * (size_t)NC + c] = tf + wavg;
  }
}

// ---------------- Stage 6: copy CLS row ----------------
__global__ __launch_bounds__(256) void cls_copy_kernel(const float* __restrict__ ff,
                                                       float* __restrict__ out) {
  int b = blockIdx.x, t = threadIdx.x;
  for (int c = t; c < NC; c += 256)
    out[(size_t)b * 257 * NC + c] = ff[(size_t)b * P1 * NC + c];
}

extern "C" void kernel_launch(void* const* d_in, const int* in_sizes, int n_in,
                              void* d_out, int out_size, void* d_ws, size_t ws_size,
                              hipStream_t stream) {
  const float* ff = (const float*)d_in[0];
  const float* q  = (const float*)d_in[1];
  const float* kk = (const float*)d_in[2];
  float* out = (float*)d_out;
  char* ws = (char*)d_ws;

  float* attn = (float*)(ws + 0);               // 8*4097*4 = 131104 B
  float* cls  = (float*)(ws + (size_t)0x40000); // 131104 B
  float* invn = (float*)(ws + (size_t)0x80000); // 131104 B
  int*   tki  = (int*)  (ws + (size_t)0xC0000); // 8*256*4 = 8192 B
  int*   nni  = (int*)  (ws + (size_t)0x100000);// 8*3840*4 = 122880 B
  float* sim  = (float*)(ws + (size_t)0x200000);// 8*256*3840*4 = 31457280 B

  int waves = NB * P1;
  int blocks = (waves * 64 + 255) / 256;
  attn_norm_kernel<<<blocks, 256, 0, stream>>>(q, kk, attn, invn);
  softmax_kernel<<<NB, 256, 0, stream>>>(attn, cls);
  topk_kernel<<<NB, 256, 0, stream>>>(cls, tki, nni);
  sim_gemm_kernel<<<dim3(NNON / 128, NT / 128, NB), 256, 0, stream>>>(kk, tki, nni, invn, sim);
  merge_kernel<<<NB * NT, 256, 0, stream>>>(ff, sim, cls, tki, nni, out);
  cls_copy_kernel<<<NB, 256, 0, stream>>>(ff, out);
}